// Round 1
// baseline (3418.687 us; speedup 1.0000x reference)
//
#include <hip/hip_runtime.h>
#include <hip/hip_bf16.h>
#include <math.h>

// Problem constants
#define B_    8
#define LP_   1024
#define CIN_  64
#define DM_   1024
#define DI_   2048
#define NS_   16
#define PH_   64
#define NH_   32
#define NL_   4
#define GG_   8
#define KH_   2048
#define DIN_  4160    // 2*DI + 2*NS + NH
#define CONVD_ 2080   // DI + 2*NS
#define L_    128     // LP/PATCH
#define R_    1024    // B_*L_
#define OUTL_ 512
#define COUT_ 64

__device__ __forceinline__ float silu_f(float x) { return x / (1.0f + expf(-x)); }

// ---------------- im2col / weight transposes ----------------
__global__ __launch_bounds__(256) void k_pre_im2col(const float* __restrict__ xp, float* __restrict__ out) {
    size_t idx = (size_t)blockIdx.x * 256 + threadIdx.x;
    if (idx >= (size_t)8192 * 320) return;
    int kk = (int)(idx % 320); size_t r = idx / 320;
    int l = (int)(r & 1023); int b = (int)(r >> 10);
    int kp = kk >> 6, c = kk & 63;
    int lp = l + kp - 2;
    float v = 0.f;
    if (lp >= 0 && lp < LP_) v = xp[((size_t)b * LP_ + lp) * CIN_ + c];
    out[idx] = v;
}

__global__ __launch_bounds__(256) void k_wpre_T(const float* __restrict__ w, float* __restrict__ out) {
    int idx = blockIdx.x * 256 + threadIdx.x;   // d*320 + kk
    if (idx >= DM_ * 320) return;
    int d = idx / 320, kk = idx % 320;
    int kp = kk >> 6, c = kk & 63;
    out[idx] = w[(d * CIN_ + c) * 5 + kp];      // pre_conv_w[d][c][kp]
}

__global__ __launch_bounds__(256) void k_wpatch_T(const float* __restrict__ w, float* __restrict__ out) {
    size_t idx = (size_t)blockIdx.x * 256 + threadIdx.x;  // d*8192 + kk
    if (idx >= (size_t)DM_ * 8192) return;
    int d = (int)(idx >> 13); int kk = (int)(idx & 8191);
    int kp = kk >> 10, din = kk & 1023;
    out[idx] = w[((size_t)d << 13) + din * 8 + kp];       // patch_w[d][din][kp]
}

// ---------------- generic fp32 tiled GEMM:  C[M,N] (+=) A[M,K] @ BT[N,K]^T ----------------
#define BKg 16
#define LDSP 68
__global__ __launch_bounds__(256) void k_gemm(const float* __restrict__ A, const float* __restrict__ BT,
                                              const float* __restrict__ bias, float* __restrict__ C,
                                              int M, int N, int K, int act, int beta) {
    __shared__ float As[BKg * LDSP];
    __shared__ float Bs[BKg * LDSP];
    int t = threadIdx.x;
    int n0 = blockIdx.x * 64, m0 = blockIdx.y * 64;
    int tm = t >> 4, tn = t & 15;
    int la_m = t >> 2;            // 0..63
    int la_k = (t & 3) * 4;       // 0,4,8,12
    const float* Arow = A + (size_t)(m0 + la_m) * K + la_k;
    const float* Brow = BT + (size_t)(n0 + la_m) * K + la_k;
    float acc[4][4] = {};
    for (int k0 = 0; k0 < K; k0 += BKg) {
        float4 av = *(const float4*)(Arow + k0);
        float4 bv = *(const float4*)(Brow + k0);
        __syncthreads();
        As[(la_k + 0) * LDSP + la_m] = av.x;
        As[(la_k + 1) * LDSP + la_m] = av.y;
        As[(la_k + 2) * LDSP + la_m] = av.z;
        As[(la_k + 3) * LDSP + la_m] = av.w;
        Bs[(la_k + 0) * LDSP + la_m] = bv.x;
        Bs[(la_k + 1) * LDSP + la_m] = bv.y;
        Bs[(la_k + 2) * LDSP + la_m] = bv.z;
        Bs[(la_k + 3) * LDSP + la_m] = bv.w;
        __syncthreads();
        #pragma unroll
        for (int kk = 0; kk < BKg; ++kk) {
            float a0 = As[kk * LDSP + tm * 4 + 0];
            float a1 = As[kk * LDSP + tm * 4 + 1];
            float a2 = As[kk * LDSP + tm * 4 + 2];
            float a3 = As[kk * LDSP + tm * 4 + 3];
            float b0 = Bs[kk * LDSP + tn * 4 + 0];
            float b1 = Bs[kk * LDSP + tn * 4 + 1];
            float b2 = Bs[kk * LDSP + tn * 4 + 2];
            float b3 = Bs[kk * LDSP + tn * 4 + 3];
            acc[0][0] += a0 * b0; acc[0][1] += a0 * b1; acc[0][2] += a0 * b2; acc[0][3] += a0 * b3;
            acc[1][0] += a1 * b0; acc[1][1] += a1 * b1; acc[1][2] += a1 * b2; acc[1][3] += a1 * b3;
            acc[2][0] += a2 * b0; acc[2][1] += a2 * b1; acc[2][2] += a2 * b2; acc[2][3] += a2 * b3;
            acc[3][0] += a3 * b0; acc[3][1] += a3 * b1; acc[3][2] += a3 * b2; acc[3][3] += a3 * b3;
        }
    }
    #pragma unroll
    for (int i = 0; i < 4; ++i) {
        int m = m0 + tm * 4 + i;
        #pragma unroll
        for (int j = 0; j < 4; ++j) {
            int n = n0 + tn * 4 + j;
            float v = acc[i][j];
            if (bias) v += bias[n];
            if (beta) v += C[(size_t)m * N + n];
            if (act == 1) v = silu_f(v);
            C[(size_t)m * N + n] = v;
        }
    }
}

// ---------------- misc elementwise ----------------
__global__ __launch_bounds__(256) void k_reverse(const float* __restrict__ hf, float* __restrict__ hb) {
    size_t idx = (size_t)blockIdx.x * 256 + threadIdx.x;
    if (idx >= (size_t)R_ * DM_) return;
    int d = (int)(idx & 1023); size_t r = idx >> 10;
    int l = (int)(r & 127); size_t b = r >> 7;
    hb[idx] = hf[((b * L_) + (L_ - 1 - l)) * DM_ + d];
}

__global__ __launch_bounds__(256) void k_rmsnorm(const float* __restrict__ h, const float* __restrict__ w,
                                                 float* __restrict__ u) {
    int r = blockIdx.x; int t = threadIdx.x;
    const float* row = h + (size_t)r * DM_;
    float v[4]; float ss = 0.f;
    #pragma unroll
    for (int i = 0; i < 4; ++i) { v[i] = row[t + 256 * i]; ss += v[i] * v[i]; }
    #pragma unroll
    for (int o = 32; o; o >>= 1) ss += __shfl_xor(ss, o);
    __shared__ float sred[4];
    if ((t & 63) == 0) sred[t >> 6] = ss;
    __syncthreads();
    float tot = sred[0] + sred[1] + sred[2] + sred[3];
    float scale = rsqrtf(tot * (1.0f / DM_) + 1e-5f);
    #pragma unroll
    for (int i = 0; i < 4; ++i) u[(size_t)r * DM_ + t + 256 * i] = v[i] * scale * w[t + 256 * i];
}

__global__ __launch_bounds__(256) void k_dtda(const float* __restrict__ zx, const float* __restrict__ dt_bias,
                                              const float* __restrict__ A_log, float* __restrict__ dt,
                                              float* __restrict__ dA) {
    int idx = blockIdx.x * 256 + threadIdx.x;
    if (idx >= R_ * NH_) return;
    int h = idx & 31; int r = idx >> 5;
    float v = zx[(size_t)r * DIN_ + 4128 + h] + dt_bias[h];
    float sp = v > 20.f ? v : log1pf(expf(v));
    dt[idx] = sp;
    dA[idx] = expf(-expf(A_log[h]) * sp);
}

__global__ __launch_bounds__(256) void k_dwconv(const float* __restrict__ zx, const float* __restrict__ cw,
                                                const float* __restrict__ cb, float* __restrict__ xbc) {
    size_t idx = (size_t)blockIdx.x * 256 + threadIdx.x;
    if (idx >= (size_t)R_ * CONVD_) return;
    int c = (int)(idx % CONVD_); int r = (int)(idx / CONVD_);
    int l = r & 127;
    float acc = cb[c];
    #pragma unroll
    for (int k = 0; k < 4; ++k) {
        int lp = l - 3 + k;
        if (lp >= 0) acc += zx[((size_t)(r - l + lp)) * DIN_ + DI_ + c] * cw[c * 4 + k];
    }
    xbc[idx] = silu_f(acc);
}

// ---------------- SSM scan: one block per (b,h) ----------------
__global__ __launch_bounds__(256) void k_scan(const float* __restrict__ xbc, const float* __restrict__ zx,
                                              const float* __restrict__ dt, const float* __restrict__ dA,
                                              const float* __restrict__ Dh, float* __restrict__ ys) {
    __shared__ float xs[L_ * PH_];     // 32 KB, holds x then y in-place
    __shared__ float Bsh[L_ * NS_];
    __shared__ float Csh[L_ * NS_];
    __shared__ float dts[L_];
    __shared__ float dAs[L_];
    int b = blockIdx.x >> 5, h = blockIdx.x & 31;
    int t = threadIdx.x;
    for (int i = t; i < L_ * PH_; i += 256) {
        int l = i >> 6, p = i & 63;
        xs[i] = xbc[((size_t)(b * L_ + l)) * CONVD_ + h * PH_ + p];
    }
    for (int i = t; i < L_ * NS_; i += 256) {
        int l = i >> 4, n = i & 15;
        Bsh[i] = xbc[((size_t)(b * L_ + l)) * CONVD_ + DI_ + n];
        Csh[i] = xbc[((size_t)(b * L_ + l)) * CONVD_ + DI_ + NS_ + n];
    }
    if (t < L_) {
        dts[t] = dt[(b * L_ + t) * NH_ + h];
        dAs[t] = dA[(b * L_ + t) * NH_ + h];
    }
    __syncthreads();
    int p = t >> 2, n0 = (t & 3) * 4;
    float Dv = Dh[h];
    float s0 = 0.f, s1 = 0.f, s2 = 0.f, s3 = 0.f;
    for (int l = 0; l < L_; ++l) {
        float x = xs[l * 64 + p];
        float dAv = dAs[l];
        float xdt = x * dts[l];
        s0 = s0 * dAv + xdt * Bsh[l * 16 + n0 + 0];
        s1 = s1 * dAv + xdt * Bsh[l * 16 + n0 + 1];
        s2 = s2 * dAv + xdt * Bsh[l * 16 + n0 + 2];
        s3 = s3 * dAv + xdt * Bsh[l * 16 + n0 + 3];
        float cp = s0 * Csh[l * 16 + n0 + 0] + s1 * Csh[l * 16 + n0 + 1]
                 + s2 * Csh[l * 16 + n0 + 2] + s3 * Csh[l * 16 + n0 + 3];
        cp += __shfl_xor(cp, 1);
        cp += __shfl_xor(cp, 2);
        if ((t & 3) == 0) xs[l * 64 + p] = cp + x * Dv;   // same-wave in-place, safe
    }
    __syncthreads();
    for (int i = t; i < L_ * PH_; i += 256) {
        int l = i >> 6, pp = i & 63;
        float z = zx[((size_t)(b * L_ + l)) * DIN_ + h * PH_ + pp];
        ys[((size_t)(b * L_ + l)) * DI_ + h * PH_ + pp] = xs[i] * silu_f(z);
    }
}

// ---------------- tail ----------------
__global__ __launch_bounds__(256) void k_meanctx(const float* __restrict__ hf, const float* __restrict__ hb,
                                                 float* __restrict__ fused) {
    int b = blockIdx.x, t = threadIdx.x;
    for (int d = t; d < DM_; d += 256) {
        float sf = 0.f, sb = 0.f;
        for (int l = 0; l < L_; ++l) {
            sf += hf[((size_t)b * L_ + l) * DM_ + d];
            sb += hb[((size_t)b * L_ + l) * DM_ + d];
        }
        fused[b * 3072 + d] = sf * (1.f / L_);
        fused[b * 3072 + DM_ + d] = sb * (1.f / L_);
    }
}

__global__ __launch_bounds__(256) void k_aux(const float* __restrict__ y_aux, const float* __restrict__ aux_w,
                                             const float* __restrict__ aux_b, float* __restrict__ fused) {
    int j = blockIdx.x * 256 + threadIdx.x;
    if (j >= DM_) return;
    for (int b = 0; b < B_; ++b) {
        float acc = aux_b[j];
        for (int a = 0; a < 32; ++a) acc += y_aux[b * 32 + a] * aux_w[j * 32 + a];
        fused[b * 3072 + 2 * DM_ + j] = silu_f(acc);
    }
}

__global__ __launch_bounds__(256) void k_basis(const float* __restrict__ x, const float* __restrict__ log_bw,
                                               float* __restrict__ basis, int Din) {
    int idx = blockIdx.x * 256 + threadIdx.x;   // b*Din + d
    if (idx >= 8 * Din) return;
    int d = idx % Din;
    float xv = x[idx];
    float bw = expf(log_bw[d]) + 1e-6f;
    float inv = 1.0f / (2.0f * bw * bw);
    #pragma unroll
    for (int g = 0; g < GG_; ++g) {
        float gg = -2.0f + g * (4.0f / 7.0f);
        float df = xv - gg;
        basis[(size_t)idx * GG_ + g] = expf(-df * df * inv);
    }
}

// wave-per-output-row dot: out[b][j] = silu( xin[b,:]·base_w[j,:] + basis[b,:]·spline_w[j,:] + base_b[j] )
__global__ __launch_bounds__(256) void k_dot(const float* __restrict__ xin, const float* __restrict__ basis,
                                             const float* __restrict__ base_w, const float* __restrict__ base_b,
                                             const float* __restrict__ spline_w, float* __restrict__ out,
                                             int Din, int Dout) {
    int wid = (blockIdx.x * 256 + threadIdx.x) >> 6;
    int lane = threadIdx.x & 63;
    if (wid >= Dout) return;
    float acc[8] = {};
    const float* wr = base_w + (size_t)wid * Din;
    for (int k = lane; k < Din; k += 64) {
        float w = wr[k];
        #pragma unroll
        for (int b = 0; b < 8; ++b) acc[b] += w * xin[(size_t)b * Din + k];
    }
    if (spline_w) {
        int Ks = Din * GG_;
        const float* sr = spline_w + (size_t)wid * Ks;
        for (int k = lane; k < Ks; k += 64) {
            float w = sr[k];
            #pragma unroll
            for (int b = 0; b < 8; ++b) acc[b] += w * basis[(size_t)b * Ks + k];
        }
    }
    #pragma unroll
    for (int b = 0; b < 8; ++b) {
        float v = acc[b];
        #pragma unroll
        for (int o = 32; o; o >>= 1) v += __shfl_xor(v, o);
        acc[b] = v;
    }
    if (lane == 0) {
        float bb = base_b[wid];
        for (int b = 0; b < 8; ++b) out[(size_t)b * Dout + wid] = silu_f(acc[b] + bb);
    }
}

__global__ __launch_bounds__(256) void k_heads(const float* __restrict__ fused, const float* __restrict__ hw,
                                               const float* __restrict__ hbias, float* __restrict__ out) {
    int wid = (blockIdx.x * 256 + threadIdx.x) >> 6;   // c*512 + l
    int lane = threadIdx.x & 63;
    if (wid >= COUT_ * OUTL_) return;
    int c = wid >> 9, l = wid & 511;
    const float* wr = hw + (size_t)wid * DM_;
    float acc[8] = {};
    for (int k = lane; k < DM_; k += 64) {
        float w = wr[k];
        #pragma unroll
        for (int b = 0; b < 8; ++b) acc[b] += w * fused[(size_t)b * DM_ + k];
    }
    #pragma unroll
    for (int b = 0; b < 8; ++b) {
        float v = acc[b];
        #pragma unroll
        for (int o = 32; o; o >>= 1) v += __shfl_xor(v, o);
        acc[b] = v;
    }
    if (lane == 0) {
        float bb = hbias[wid];
        for (int b = 0; b < 8; ++b) out[((size_t)b * OUTL_ + l) * COUT_ + c] = acc[b] + bb;
    }
}

// ---------------- launch ----------------
extern "C" void kernel_launch(void* const* d_in, const int* in_sizes, int n_in,
                              void* d_out, int out_size, void* d_ws, size_t ws_size,
                              hipStream_t stream) {
    const float* x_prefix = (const float*)d_in[0];
    const float* y_aux    = (const float*)d_in[1];
    const float* pre_w    = (const float*)d_in[2];
    const float* pre_b    = (const float*)d_in[3];
    const float* patch_w  = (const float*)d_in[4];
    const float* patch_b  = (const float*)d_in[5];
    const float* norm_w[2] = {(const float*)d_in[6],  (const float*)d_in[14]};
    const float* in_w[2]   = {(const float*)d_in[7],  (const float*)d_in[15]};
    const float* conv_w[2] = {(const float*)d_in[8],  (const float*)d_in[16]};
    const float* conv_b[2] = {(const float*)d_in[9],  (const float*)d_in[17]};
    const float* A_log[2]  = {(const float*)d_in[10], (const float*)d_in[18]};
    const float* Dvec[2]   = {(const float*)d_in[11], (const float*)d_in[19]};
    const float* dt_b[2]   = {(const float*)d_in[12], (const float*)d_in[20]};
    const float* out_w[2]  = {(const float*)d_in[13], (const float*)d_in[21]};
    const float* aux_w = (const float*)d_in[22];
    const float* aux_b = (const float*)d_in[23];
    const float* k1_lbw = (const float*)d_in[24];
    const float* k1_bw  = (const float*)d_in[25];
    const float* k1_bb  = (const float*)d_in[26];
    const float* k1_sw  = (const float*)d_in[27];
    const float* k2_lbw = (const float*)d_in[28];
    const float* k2_bw  = (const float*)d_in[29];
    const float* k2_bb  = (const float*)d_in[30];
    const float* k2_sw  = (const float*)d_in[31];
    const float* sh_w = (const float*)d_in[32];
    const float* sh_b = (const float*)d_in[33];
    const float* hw   = (const float*)d_in[34];
    const float* hbias= (const float*)d_in[35];
    float* ws = (float*)d_ws;
    float* out = (float*)d_out;

    // workspace layout (floats). Stage-A/B scratch is overlaid by mamba temps.
    const size_t o_Apre = 0;                 // 8192*320
    const size_t o_wpreT = 2621440;          // 1024*320
    const size_t o_x1 = 2949120;             // 8192*1024
    const size_t o_wpatchT = 11337728;       // 1024*8192
    const size_t o_u   = 0;                  // 1024*1024   (overlay)
    const size_t o_zx  = 1048576;            // 1024*4160
    const size_t o_xbc = 5308416;            // 1024*2080
    const size_t o_dt  = 7438336;            // 1024*32
    const size_t o_dA  = 7471104;            // 1024*32
    const size_t o_ys  = 7503872;            // 1024*2048
    const size_t o_hf  = 19726336;           // 1024*1024
    const size_t o_hb  = 20774912;           // 1024*1024
    const size_t o_f1  = 21823488;           // 8*3072
    const size_t o_bas1= 21848064;           // 8*24576
    const size_t o_k1  = 22044672;           // 8*2048
    const size_t o_bas2= 22061056;           // 8*16384
    const size_t o_k2  = 22192128;           // 8*1024
    const size_t o_f4  = 22200320;           // 8*1024
    const size_t total_f = 22208512;
    if (ws_size < total_f * sizeof(float)) return;  // insufficient scratch -> fail loudly

    // Stage A: pre-conv as GEMM (im2col), silu fused in epilogue
    k_pre_im2col<<<10240, 256, 0, stream>>>(x_prefix, ws + o_Apre);
    k_wpre_T<<<1280, 256, 0, stream>>>(pre_w, ws + o_wpreT);
    k_gemm<<<dim3(16, 128), 256, 0, stream>>>(ws + o_Apre, ws + o_wpreT, pre_b, ws + o_x1,
                                              8192, 1024, 320, 1, 0);
    // Stage B: patch conv as contiguous GEMM -> h_f, then reverse -> h_b
    k_wpatch_T<<<32768, 256, 0, stream>>>(patch_w, ws + o_wpatchT);
    k_gemm<<<dim3(16, 16), 256, 0, stream>>>(ws + o_x1, ws + o_wpatchT, patch_b, ws + o_hf,
                                             1024, 1024, 8192, 0, 0);
    k_reverse<<<4096, 256, 0, stream>>>(ws + o_hf, ws + o_hb);

    // Mamba stacks (fwd on h_f, bwd on h_b)
    for (int dir = 0; dir < 2; ++dir) {
        float* h = ws + (dir == 0 ? o_hf : o_hb);
        for (int i = 0; i < NL_; ++i) {
            k_rmsnorm<<<1024, 256, 0, stream>>>(h, norm_w[dir] + (size_t)i * DM_, ws + o_u);
            k_gemm<<<dim3(65, 16), 256, 0, stream>>>(ws + o_u, in_w[dir] + (size_t)i * DIN_ * DM_,
                                                     nullptr, ws + o_zx, 1024, DIN_, DM_, 0, 0);
            k_dtda<<<128, 256, 0, stream>>>(ws + o_zx, dt_b[dir] + i * NH_, A_log[dir] + i * NH_,
                                            ws + o_dt, ws + o_dA);
            k_dwconv<<<8320, 256, 0, stream>>>(ws + o_zx, conv_w[dir] + (size_t)i * CONVD_ * 4,
                                               conv_b[dir] + (size_t)i * CONVD_, ws + o_xbc);
            k_scan<<<256, 256, 0, stream>>>(ws + o_xbc, ws + o_zx, ws + o_dt, ws + o_dA,
                                            Dvec[dir] + i * NH_, ws + o_ys);
            k_gemm<<<dim3(16, 16), 256, 0, stream>>>(ws + o_ys, out_w[dir] + (size_t)i * DM_ * DI_,
                                                     nullptr, h, 1024, DM_, DI_, 0, 1);
        }
    }

    // Tail: means + aux -> fused(8,3072) -> KAN1 -> KAN2 -> shared -> heads
    k_meanctx<<<8, 256, 0, stream>>>(ws + o_hf, ws + o_hb, ws + o_f1);
    k_aux<<<4, 256, 0, stream>>>(y_aux, aux_w, aux_b, ws + o_f1);
    k_basis<<<96, 256, 0, stream>>>(ws + o_f1, k1_lbw, ws + o_bas1, 3072);
    k_dot<<<512, 256, 0, stream>>>(ws + o_f1, ws + o_bas1, k1_bw, k1_bb, k1_sw, ws + o_k1, 3072, 2048);
    k_basis<<<64, 256, 0, stream>>>(ws + o_k1, k2_lbw, ws + o_bas2, 2048);
    k_dot<<<256, 256, 0, stream>>>(ws + o_k1, ws + o_bas2, k2_bw, k2_bb, k2_sw, ws + o_k2, 2048, 1024);
    k_dot<<<256, 256, 0, stream>>>(ws + o_k2, nullptr, sh_w, sh_b, nullptr, ws + o_f4, 1024, 1024);
    k_heads<<<8192, 256, 0, stream>>>(ws + o_f4, hw, hbias, out);
}

// Round 2
// 1637.410 us; speedup vs baseline: 2.0879x; 2.0879x over previous
//
#include <hip/hip_runtime.h>
#include <hip/hip_bf16.h>
#include <math.h>

// Problem constants
#define B_    8
#define LP_   1024
#define CIN_  64
#define DM_   1024
#define DI_   2048
#define NS_   16
#define PH_   64
#define NH_   32
#define NL_   4
#define GG_   8
#define KH_   2048
#define DIN_  4160    // 2*DI + 2*NS + NH
#define NPAD_ 4224    // DIN_ padded to /128
#define CONVD_ 2080   // DI + 2*NS
#define L_    128     // LP/PATCH
#define R_    1024    // B_*L_
#define OUTL_ 512
#define COUT_ 64

typedef __bf16 bf16x8 __attribute__((ext_vector_type(8)));
typedef float f32x4 __attribute__((ext_vector_type(4)));
typedef unsigned short ushort;

__device__ __forceinline__ float silu_f(float x) { return x / (1.0f + expf(-x)); }

__device__ __forceinline__ void gload_lds16(const void* g, void* l) {
    __builtin_amdgcn_global_load_lds((const __attribute__((address_space(1))) unsigned int*)g,
                                     (__attribute__((address_space(3))) unsigned int*)l, 16, 0, 0);
}

// ---------------- conversions / im2col / weight transposes (bf16 out) ----------------
__global__ __launch_bounds__(256) void k_pre_im2col(const float* __restrict__ xp, __hip_bfloat16* __restrict__ out) {
    size_t idx = (size_t)blockIdx.x * 256 + threadIdx.x;
    if (idx >= (size_t)8192 * 320) return;
    int kk = (int)(idx % 320); size_t r = idx / 320;
    int l = (int)(r & 1023); int b = (int)(r >> 10);
    int kp = kk >> 6, c = kk & 63;
    int lp = l + kp - 2;
    float v = 0.f;
    if (lp >= 0 && lp < LP_) v = xp[((size_t)b * LP_ + lp) * CIN_ + c];
    out[idx] = __float2bfloat16(v);
}

__global__ __launch_bounds__(256) void k_wpre_T(const float* __restrict__ w, __hip_bfloat16* __restrict__ out) {
    int idx = blockIdx.x * 256 + threadIdx.x;   // d*320 + kk
    if (idx >= DM_ * 320) return;
    int d = idx / 320, kk = idx % 320;
    int kp = kk >> 6, c = kk & 63;
    out[idx] = __float2bfloat16(w[(d * CIN_ + c) * 5 + kp]);   // pre_conv_w[d][c][kp]
}

__global__ __launch_bounds__(256) void k_wpatch_T(const float* __restrict__ w, __hip_bfloat16* __restrict__ out) {
    size_t idx = (size_t)blockIdx.x * 256 + threadIdx.x;  // d*8192 + kk
    if (idx >= (size_t)DM_ * 8192) return;
    int d = (int)(idx >> 13); int kk = (int)(idx & 8191);
    int kp = kk >> 10, din = kk & 1023;
    out[idx] = __float2bfloat16(w[((size_t)d << 13) + din * 8 + kp]);  // patch_w[d][din][kp]
}

// in_w layer [4160][1024] fp32 -> [4224][1024] bf16 (pad rows zero)
__global__ __launch_bounds__(256) void k_cvt_pad(const float* __restrict__ src, __hip_bfloat16* __restrict__ dst) {
    int idx = (blockIdx.x * 256 + threadIdx.x) * 4;
    if (idx >= NPAD_ * 1024) return;
    int row = idx >> 10;
    if (row < DIN_) {
        float4 v = *(const float4*)(src + idx);
        dst[idx + 0] = __float2bfloat16(v.x);
        dst[idx + 1] = __float2bfloat16(v.y);
        dst[idx + 2] = __float2bfloat16(v.z);
        dst[idx + 3] = __float2bfloat16(v.w);
    } else {
        dst[idx + 0] = __float2bfloat16(0.f);
        dst[idx + 1] = __float2bfloat16(0.f);
        dst[idx + 2] = __float2bfloat16(0.f);
        dst[idx + 3] = __float2bfloat16(0.f);
    }
}

__global__ __launch_bounds__(256) void k_cvt4(const float* __restrict__ src, __hip_bfloat16* __restrict__ dst, int n4) {
    int i = blockIdx.x * 256 + threadIdx.x;
    if (i >= n4) return;
    int idx = i * 4;
    float4 v = *(const float4*)(src + idx);
    dst[idx + 0] = __float2bfloat16(v.x);
    dst[idx + 1] = __float2bfloat16(v.y);
    dst[idx + 2] = __float2bfloat16(v.z);
    dst[idx + 3] = __float2bfloat16(v.w);
}

// ---------------- bf16 MFMA GEMM:  C[M,Nstore] = A[M,K] @ BT[Npad,K]^T (+bias)(+resid)(act) ----------------
// 256 threads = 4 waves (2x2), wave tile (BM/2)x(BN/2), 16x16x32 bf16 MFMA, BK=32.
template<int BM, int BN>
__global__ __launch_bounds__(256) void k_gemm_mfma(
    const ushort* __restrict__ A, const ushort* __restrict__ BT,
    const float* __restrict__ bias, const float* __restrict__ resid,
    float* __restrict__ Cf, __hip_bfloat16* __restrict__ Cb,
    int M, int K, int ldc, int Nstore, int act)
{
    constexpr int BK = 32;
    constexpr int WM = BM / 2, WN = BN / 2;
    constexpr int MR = WM / 16, NR = WN / 16;
    constexpr int ACH = BM * BK / 8;   // 16B chunks in A tile
    constexpr int BCH = BN * BK / 8;
    __shared__ ushort sA[BM * BK];
    __shared__ ushort sB[BN * BK];
    int tid = threadIdx.x;
    int lane = tid & 63, w = tid >> 6;
    int wr = w >> 1, wc = w & 1;
    int m0 = blockIdx.y * BM, n0 = blockIdx.x * BN;

    f32x4 acc[MR][NR] = {};
    for (int k0 = 0; k0 < K; k0 += BK) {
        __syncthreads();
        #pragma unroll
        for (int c = tid; c < ACH; c += 256) {
            int row = c >> 2, col = (c & 3) * 8;
            gload_lds16(A + (size_t)(m0 + row) * K + k0 + col, (char*)sA + c * 16);
        }
        #pragma unroll
        for (int c = tid; c < BCH; c += 256) {
            int row = c >> 2, col = (c & 3) * 8;
            gload_lds16(BT + (size_t)(n0 + row) * K + k0 + col, (char*)sB + c * 16);
        }
        __syncthreads();   // drains vmcnt (global_load_lds) per compiler semantics
        bf16x8 af[MR], bfr[NR];
        #pragma unroll
        for (int m = 0; m < MR; ++m)
            af[m] = *(const bf16x8*)&sA[(wr * WM + m * 16 + (lane & 15)) * BK + (lane >> 4) * 8];
        #pragma unroll
        for (int n = 0; n < NR; ++n)
            bfr[n] = *(const bf16x8*)&sB[(wc * WN + n * 16 + (lane & 15)) * BK + (lane >> 4) * 8];
        #pragma unroll
        for (int m = 0; m < MR; ++m)
            #pragma unroll
            for (int n = 0; n < NR; ++n)
                acc[m][n] = __builtin_amdgcn_mfma_f32_16x16x32_bf16(af[m], bfr[n], acc[m][n], 0, 0, 0);
    }
    // epilogue: C row = (lane>>4)*4 + j, col = lane&15  [verified m89/m91 mapping]
    #pragma unroll
    for (int m = 0; m < MR; ++m) {
        int row = m0 + wr * WM + m * 16 + (lane >> 4) * 4;
        #pragma unroll
        for (int n = 0; n < NR; ++n) {
            int col = n0 + wc * WN + n * 16 + (lane & 15);
            if (col < Nstore) {
                float bv = bias ? bias[col] : 0.f;
                #pragma unroll
                for (int j = 0; j < 4; ++j) {
                    float v = acc[m][n][j] + bv;
                    if (resid) v += resid[(size_t)(row + j) * ldc + col];
                    if (act) v = silu_f(v);
                    if (Cb) Cb[(size_t)(row + j) * ldc + col] = __float2bfloat16(v);
                    else    Cf[(size_t)(row + j) * ldc + col] = v;
                }
            }
        }
    }
}

// ---------------- misc elementwise ----------------
__global__ __launch_bounds__(256) void k_reverse(const float* __restrict__ hf, float* __restrict__ hb) {
    size_t idx = (size_t)blockIdx.x * 256 + threadIdx.x;
    if (idx >= (size_t)R_ * DM_) return;
    int d = (int)(idx & 1023); size_t r = idx >> 10;
    int l = (int)(r & 127); size_t b = r >> 7;
    hb[idx] = hf[((b * L_) + (L_ - 1 - l)) * DM_ + d];
}

__global__ __launch_bounds__(256) void k_rmsnorm(const float* __restrict__ h, const float* __restrict__ w,
                                                 __hip_bfloat16* __restrict__ u) {
    int r = blockIdx.x; int t = threadIdx.x;
    const float* row = h + (size_t)r * DM_;
    float v[4]; float ss = 0.f;
    #pragma unroll
    for (int i = 0; i < 4; ++i) { v[i] = row[t + 256 * i]; ss += v[i] * v[i]; }
    #pragma unroll
    for (int o = 32; o; o >>= 1) ss += __shfl_xor(ss, o);
    __shared__ float sred[4];
    if ((t & 63) == 0) sred[t >> 6] = ss;
    __syncthreads();
    float tot = sred[0] + sred[1] + sred[2] + sred[3];
    float scale = rsqrtf(tot * (1.0f / DM_) + 1e-5f);
    #pragma unroll
    for (int i = 0; i < 4; ++i)
        u[(size_t)r * DM_ + t + 256 * i] = __float2bfloat16(v[i] * scale * w[t + 256 * i]);
}

__global__ __launch_bounds__(256) void k_dtda(const float* __restrict__ zx, const float* __restrict__ dt_bias,
                                              const float* __restrict__ A_log, float* __restrict__ dt,
                                              float* __restrict__ dA) {
    int idx = blockIdx.x * 256 + threadIdx.x;
    if (idx >= R_ * NH_) return;
    int h = idx & 31; int r = idx >> 5;
    float v = zx[(size_t)r * DIN_ + 4128 + h] + dt_bias[h];
    float sp = v > 20.f ? v : log1pf(expf(v));
    dt[idx] = sp;
    dA[idx] = expf(-expf(A_log[h]) * sp);
}

__global__ __launch_bounds__(256) void k_dwconv(const float* __restrict__ zx, const float* __restrict__ cw,
                                                const float* __restrict__ cb, float* __restrict__ xbc) {
    size_t idx = (size_t)blockIdx.x * 256 + threadIdx.x;
    if (idx >= (size_t)R_ * CONVD_) return;
    int c = (int)(idx % CONVD_); int r = (int)(idx / CONVD_);
    int l = r & 127;
    float acc = cb[c];
    #pragma unroll
    for (int k = 0; k < 4; ++k) {
        int lp = l - 3 + k;
        if (lp >= 0) acc += zx[((size_t)(r - l + lp)) * DIN_ + DI_ + c] * cw[c * 4 + k];
    }
    xbc[idx] = silu_f(acc);
}

// ---------------- SSM scan: one block per (b,h) ----------------
__global__ __launch_bounds__(256) void k_scan(const float* __restrict__ xbc, const float* __restrict__ zx,
                                              const float* __restrict__ dt, const float* __restrict__ dA,
                                              const float* __restrict__ Dh, __hip_bfloat16* __restrict__ ys) {
    __shared__ float xs[L_ * PH_];     // 32 KB, holds x then y in-place
    __shared__ float Bsh[L_ * NS_];
    __shared__ float Csh[L_ * NS_];
    __shared__ float dts[L_];
    __shared__ float dAs[L_];
    int b = blockIdx.x >> 5, h = blockIdx.x & 31;
    int t = threadIdx.x;
    for (int i = t; i < L_ * PH_; i += 256) {
        int l = i >> 6, p = i & 63;
        xs[i] = xbc[((size_t)(b * L_ + l)) * CONVD_ + h * PH_ + p];
    }
    for (int i = t; i < L_ * NS_; i += 256) {
        int l = i >> 4, n = i & 15;
        Bsh[i] = xbc[((size_t)(b * L_ + l)) * CONVD_ + DI_ + n];
        Csh[i] = xbc[((size_t)(b * L_ + l)) * CONVD_ + DI_ + NS_ + n];
    }
    if (t < L_) {
        dts[t] = dt[(b * L_ + t) * NH_ + h];
        dAs[t] = dA[(b * L_ + t) * NH_ + h];
    }
    __syncthreads();
    int p = t >> 2, n0 = (t & 3) * 4;
    float Dv = Dh[h];
    float s0 = 0.f, s1 = 0.f, s2 = 0.f, s3 = 0.f;
    for (int l = 0; l < L_; ++l) {
        float x = xs[l * 64 + p];
        float dAv = dAs[l];
        float xdt = x * dts[l];
        s0 = s0 * dAv + xdt * Bsh[l * 16 + n0 + 0];
        s1 = s1 * dAv + xdt * Bsh[l * 16 + n0 + 1];
        s2 = s2 * dAv + xdt * Bsh[l * 16 + n0 + 2];
        s3 = s3 * dAv + xdt * Bsh[l * 16 + n0 + 3];
        float cp = s0 * Csh[l * 16 + n0 + 0] + s1 * Csh[l * 16 + n0 + 1]
                 + s2 * Csh[l * 16 + n0 + 2] + s3 * Csh[l * 16 + n0 + 3];
        cp += __shfl_xor(cp, 1);
        cp += __shfl_xor(cp, 2);
        if ((t & 3) == 0) xs[l * 64 + p] = cp + x * Dv;   // same-wave in-place, safe
    }
    __syncthreads();
    for (int i = t; i < L_ * PH_; i += 256) {
        int l = i >> 6, pp = i & 63;
        float z = zx[((size_t)(b * L_ + l)) * DIN_ + h * PH_ + pp];
        ys[((size_t)(b * L_ + l)) * DI_ + h * PH_ + pp] = __float2bfloat16(xs[i] * silu_f(z));
    }
}

// ---------------- tail ----------------
__global__ __launch_bounds__(256) void k_meanctx(const float* __restrict__ hf, const float* __restrict__ hb,
                                                 float* __restrict__ fused) {
    int b = blockIdx.x, t = threadIdx.x;
    for (int d = t; d < DM_; d += 256) {
        float sf = 0.f, sb = 0.f;
        for (int l = 0; l < L_; ++l) {
            sf += hf[((size_t)b * L_ + l) * DM_ + d];
            sb += hb[((size_t)b * L_ + l) * DM_ + d];
        }
        fused[b * 3072 + d] = sf * (1.f / L_);
        fused[b * 3072 + DM_ + d] = sb * (1.f / L_);
    }
}

__global__ __launch_bounds__(256) void k_aux(const float* __restrict__ y_aux, const float* __restrict__ aux_w,
                                             const float* __restrict__ aux_b, float* __restrict__ fused) {
    int j = blockIdx.x * 256 + threadIdx.x;
    if (j >= DM_) return;
    for (int b = 0; b < B_; ++b) {
        float acc = aux_b[j];
        for (int a = 0; a < 32; ++a) acc += y_aux[b * 32 + a] * aux_w[j * 32 + a];
        fused[b * 3072 + 2 * DM_ + j] = silu_f(acc);
    }
}

__global__ __launch_bounds__(256) void k_basis(const float* __restrict__ x, const float* __restrict__ log_bw,
                                               float* __restrict__ basis, int Din) {
    int idx = blockIdx.x * 256 + threadIdx.x;   // b*Din + d
    if (idx >= 8 * Din) return;
    int d = idx % Din;
    float xv = x[idx];
    float bw = expf(log_bw[d]) + 1e-6f;
    float inv = 1.0f / (2.0f * bw * bw);
    #pragma unroll
    for (int g = 0; g < GG_; ++g) {
        float gg = -2.0f + g * (4.0f / 7.0f);
        float df = xv - gg;
        basis[(size_t)idx * GG_ + g] = expf(-df * df * inv);
    }
}

__global__ __launch_bounds__(256) void k_dot(const float* __restrict__ xin, const float* __restrict__ basis,
                                             const float* __restrict__ base_w, const float* __restrict__ base_b,
                                             const float* __restrict__ spline_w, float* __restrict__ out,
                                             int Din, int Dout) {
    int wid = (blockIdx.x * 256 + threadIdx.x) >> 6;
    int lane = threadIdx.x & 63;
    if (wid >= Dout) return;
    float acc[8] = {};
    const float* wr = base_w + (size_t)wid * Din;
    for (int k = lane; k < Din; k += 64) {
        float w = wr[k];
        #pragma unroll
        for (int b = 0; b < 8; ++b) acc[b] += w * xin[(size_t)b * Din + k];
    }
    if (spline_w) {
        int Ks = Din * GG_;
        const float* sr = spline_w + (size_t)wid * Ks;
        for (int k = lane; k < Ks; k += 64) {
            float w = sr[k];
            #pragma unroll
            for (int b = 0; b < 8; ++b) acc[b] += w * basis[(size_t)b * Ks + k];
        }
    }
    #pragma unroll
    for (int b = 0; b < 8; ++b) {
        float v = acc[b];
        #pragma unroll
        for (int o = 32; o; o >>= 1) v += __shfl_xor(v, o);
        acc[b] = v;
    }
    if (lane == 0) {
        float bb = base_b[wid];
        for (int b = 0; b < 8; ++b) out[(size_t)b * Dout + wid] = silu_f(acc[b] + bb);
    }
}

__global__ __launch_bounds__(256) void k_heads(const float* __restrict__ fused, const float* __restrict__ hw,
                                               const float* __restrict__ hbias, float* __restrict__ out) {
    int wid = (blockIdx.x * 256 + threadIdx.x) >> 6;   // c*512 + l
    int lane = threadIdx.x & 63;
    if (wid >= COUT_ * OUTL_) return;
    int c = wid >> 9, l = wid & 511;
    const float* wr = hw + (size_t)wid * DM_;
    float acc[8] = {};
    for (int k = lane; k < DM_; k += 64) {
        float w = wr[k];
        #pragma unroll
        for (int b = 0; b < 8; ++b) acc[b] += w * fused[(size_t)b * DM_ + k];
    }
    #pragma unroll
    for (int b = 0; b < 8; ++b) {
        float v = acc[b];
        #pragma unroll
        for (int o = 32; o; o >>= 1) v += __shfl_xor(v, o);
        acc[b] = v;
    }
    if (lane == 0) {
        float bb = hbias[wid];
        for (int b = 0; b < 8; ++b) out[((size_t)b * OUTL_ + l) * COUT_ + c] = acc[b] + bb;
    }
}

// ---------------- launch ----------------
extern "C" void kernel_launch(void* const* d_in, const int* in_sizes, int n_in,
                              void* d_out, int out_size, void* d_ws, size_t ws_size,
                              hipStream_t stream) {
    const float* x_prefix = (const float*)d_in[0];
    const float* y_aux    = (const float*)d_in[1];
    const float* pre_w    = (const float*)d_in[2];
    const float* pre_b    = (const float*)d_in[3];
    const float* patch_w  = (const float*)d_in[4];
    const float* patch_b  = (const float*)d_in[5];
    const float* norm_w[2] = {(const float*)d_in[6],  (const float*)d_in[14]};
    const float* in_w[2]   = {(const float*)d_in[7],  (const float*)d_in[15]};
    const float* conv_w[2] = {(const float*)d_in[8],  (const float*)d_in[16]};
    const float* conv_b[2] = {(const float*)d_in[9],  (const float*)d_in[17]};
    const float* A_log[2]  = {(const float*)d_in[10], (const float*)d_in[18]};
    const float* Dvec[2]   = {(const float*)d_in[11], (const float*)d_in[19]};
    const float* dt_b[2]   = {(const float*)d_in[12], (const float*)d_in[20]};
    const float* out_w[2]  = {(const float*)d_in[13], (const float*)d_in[21]};
    const float* aux_w = (const float*)d_in[22];
    const float* aux_b = (const float*)d_in[23];
    const float* k1_lbw = (const float*)d_in[24];
    const float* k1_bw  = (const float*)d_in[25];
    const float* k1_bb  = (const float*)d_in[26];
    const float* k1_sw  = (const float*)d_in[27];
    const float* k2_lbw = (const float*)d_in[28];
    const float* k2_bw  = (const float*)d_in[29];
    const float* k2_bb  = (const float*)d_in[30];
    const float* k2_sw  = (const float*)d_in[31];
    const float* sh_w = (const float*)d_in[32];
    const float* sh_b = (const float*)d_in[33];
    const float* hw   = (const float*)d_in[34];
    const float* hbias= (const float*)d_in[35];
    float* ws = (float*)d_ws;
    float* out = (float*)d_out;

    // workspace layout (float units). Stage region [0..9,863,168) is overlaid by the mamba region.
    const size_t o_ApreB   = 0;           // bf16 8192x320   -> 1,310,720 f
    const size_t o_wpreTB  = 1310720;     // bf16 1024x320   ->   163,840 f
    const size_t o_x1B     = 1474560;     // bf16 8192x1024  -> 4,194,304 f
    const size_t o_wpatchTB= 5668864;     // bf16 1024x8192  -> 4,194,304 f
    // mamba overlay (starts after stage is dead):
    const size_t o_uB   = 0;              // bf16 1024x1024  ->   524,288 f
    const size_t o_zx   = 524288;         // f32 1024x4160   -> 4,259,840 f
    const size_t o_xbc  = 4784128;        // f32 1024x2080   -> 2,129,920 f
    const size_t o_dt   = 6914048;        // f32 1024x32
    const size_t o_dA   = 6946816;        // f32 1024x32
    const size_t o_ysB  = 6979584;        // bf16 1024x2048  -> 1,048,576 f
    const size_t o_wBB  = 8028160;        // bf16 4224x1024  -> 2,162,688 f
    const size_t o_wOB  = 10190848;       // bf16 1024x2048  -> 1,048,576 f
    const size_t o_hf   = 11239424;       // f32 1024x1024
    const size_t o_hb   = 12288000;       // f32 1024x1024
    const size_t o_f1   = 13336576;       // 8x3072
    const size_t o_bas1 = 13361152;       // 8x24576
    const size_t o_k1   = 13557760;       // 8x2048
    const size_t o_bas2 = 13574144;       // 8x16384
    const size_t o_k2   = 13705216;       // 8x1024
    const size_t o_f4   = 13713408;       // 8x1024
    const size_t total_f = 13721600;
    if (ws_size < total_f * sizeof(float)) return;

    __hip_bfloat16* ApreB   = (__hip_bfloat16*)(ws + o_ApreB);
    __hip_bfloat16* wpreTB  = (__hip_bfloat16*)(ws + o_wpreTB);
    __hip_bfloat16* x1B     = (__hip_bfloat16*)(ws + o_x1B);
    __hip_bfloat16* wpatchTB= (__hip_bfloat16*)(ws + o_wpatchTB);
    __hip_bfloat16* uB      = (__hip_bfloat16*)(ws + o_uB);
    __hip_bfloat16* ysB     = (__hip_bfloat16*)(ws + o_ysB);
    __hip_bfloat16* wBB     = (__hip_bfloat16*)(ws + o_wBB);
    __hip_bfloat16* wOB     = (__hip_bfloat16*)(ws + o_wOB);

    // Stage A: pre-conv as im2col GEMM (silu fused), bf16 out
    k_wpre_T<<<1280, 256, 0, stream>>>(pre_w, wpreTB);
    k_wpatch_T<<<32768, 256, 0, stream>>>(patch_w, wpatchTB);
    k_pre_im2col<<<10240, 256, 0, stream>>>(x_prefix, ApreB);
    k_gemm_mfma<128,128><<<dim3(8, 64), 256, 0, stream>>>(
        (const ushort*)ApreB, (const ushort*)wpreTB, pre_b, nullptr, nullptr, x1B,
        8192, 320, 1024, 1024, 1);
    // Stage B: patch conv as GEMM -> h_f (fp32), then reverse -> h_b
    k_gemm_mfma<64,64><<<dim3(16, 16), 256, 0, stream>>>(
        (const ushort*)x1B, (const ushort*)wpatchTB, patch_b, nullptr, ws + o_hf, nullptr,
        1024, 8192, 1024, 1024, 0);
    k_reverse<<<4096, 256, 0, stream>>>(ws + o_hf, ws + o_hb);

    // Mamba stacks
    for (int dir = 0; dir < 2; ++dir) {
        float* h = ws + (dir == 0 ? o_hf : o_hb);
        for (int i = 0; i < NL_; ++i) {
            k_rmsnorm<<<1024, 256, 0, stream>>>(h, norm_w[dir] + (size_t)i * DM_, uB);
            k_cvt_pad<<<NPAD_, 256, 0, stream>>>(in_w[dir] + (size_t)i * DIN_ * DM_, wBB);
            k_gemm_mfma<128,128><<<dim3(33, 8), 256, 0, stream>>>(
                (const ushort*)uB, (const ushort*)wBB, nullptr, nullptr, ws + o_zx, nullptr,
                1024, 1024, DIN_, DIN_, 0);
            k_dtda<<<128, 256, 0, stream>>>(ws + o_zx, dt_b[dir] + i * NH_, A_log[dir] + i * NH_,
                                            ws + o_dt, ws + o_dA);
            k_dwconv<<<8320, 256, 0, stream>>>(ws + o_zx, conv_w[dir] + (size_t)i * CONVD_ * 4,
                                               conv_b[dir] + (size_t)i * CONVD_, ws + o_xbc);
            k_cvt4<<<2048, 256, 0, stream>>>(out_w[dir] + (size_t)i * DM_ * DI_, wOB, DM_ * DI_ / 4);
            k_scan<<<256, 256, 0, stream>>>(ws + o_xbc, ws + o_zx, ws + o_dt, ws + o_dA,
                                            Dvec[dir] + i * NH_, ysB);
            k_gemm_mfma<64,64><<<dim3(16, 16), 256, 0, stream>>>(
                (const ushort*)ysB, (const ushort*)wOB, nullptr, h, h, nullptr,
                1024, 2048, 1024, 1024, 0);
        }
    }

    // Tail
    k_meanctx<<<8, 256, 0, stream>>>(ws + o_hf, ws + o_hb, ws + o_f1);
    k_aux<<<4, 256, 0, stream>>>(y_aux, aux_w, aux_b, ws + o_f1);
    k_basis<<<96, 256, 0, stream>>>(ws + o_f1, k1_lbw, ws + o_bas1, 3072);
    k_dot<<<512, 256, 0, stream>>>(ws + o_f1, ws + o_bas1, k1_bw, k1_bb, k1_sw, ws + o_k1, 3072, 2048);
    k_basis<<<64, 256, 0, stream>>>(ws + o_k1, k2_lbw, ws + o_bas2, 2048);
    k_dot<<<256, 256, 0, stream>>>(ws + o_k1, ws + o_bas2, k2_bw, k2_bb, k2_sw, ws + o_k2, 2048, 1024);
    k_dot<<<256, 256, 0, stream>>>(ws + o_k2, nullptr, sh_w, sh_b, nullptr, ws + o_f4, 1024, 1024);
    k_heads<<<8192, 256, 0, stream>>>(ws + o_f4, hw, hbias, out);
}

// Round 3
// 1407.918 us; speedup vs baseline: 2.4282x; 1.1630x over previous
//
#include <hip/hip_runtime.h>
#include <hip/hip_bf16.h>
#include <math.h>

// Problem constants
#define B_    8
#define LP_   1024
#define CIN_  64
#define DM_   1024
#define DI_   2048
#define NS_   16
#define PH_   64
#define NH_   32
#define NL_   4
#define GG_   8
#define KH_   2048
#define DIN_  4160    // 2*DI + 2*NS + NH
#define NPAD_ 4224    // DIN_ padded to /128
#define CONVD_ 2080   // DI + 2*NS
#define L_    128     // LP/PATCH
#define R_    1024    // B_*L_
#define OUTL_ 512
#define COUT_ 64

typedef __bf16 bf16x8 __attribute__((ext_vector_type(8)));
typedef float f32x4 __attribute__((ext_vector_type(4)));
typedef unsigned short ushort;

__device__ __forceinline__ float silu_f(float x) { return x / (1.0f + expf(-x)); }

__device__ __forceinline__ void gload_lds16(const void* g, void* l) {
    __builtin_amdgcn_global_load_lds((const __attribute__((address_space(1))) unsigned int*)g,
                                     (__attribute__((address_space(3))) unsigned int*)l, 16, 0, 0);
}

// ---------------- conversions / im2col / weight transposes (bf16 out) ----------------
__global__ __launch_bounds__(256) void k_pre_im2col(const float* __restrict__ xp, __hip_bfloat16* __restrict__ out) {
    size_t idx = (size_t)blockIdx.x * 256 + threadIdx.x;
    if (idx >= (size_t)8192 * 320) return;
    int kk = (int)(idx % 320); size_t r = idx / 320;
    int l = (int)(r & 1023); int b = (int)(r >> 10);
    int kp = kk >> 6, c = kk & 63;
    int lp = l + kp - 2;
    float v = 0.f;
    if (lp >= 0 && lp < LP_) v = xp[((size_t)b * LP_ + lp) * CIN_ + c];
    out[idx] = __float2bfloat16(v);
}

__global__ __launch_bounds__(256) void k_wpre_T(const float* __restrict__ w, __hip_bfloat16* __restrict__ out) {
    int idx = blockIdx.x * 256 + threadIdx.x;   // d*320 + kk
    if (idx >= DM_ * 320) return;
    int d = idx / 320, kk = idx % 320;
    int kp = kk >> 6, c = kk & 63;
    out[idx] = __float2bfloat16(w[(d * CIN_ + c) * 5 + kp]);   // pre_conv_w[d][c][kp]
}

__global__ __launch_bounds__(256) void k_wpatch_T(const float* __restrict__ w, __hip_bfloat16* __restrict__ out) {
    size_t idx = (size_t)blockIdx.x * 256 + threadIdx.x;  // d*8192 + kk
    if (idx >= (size_t)DM_ * 8192) return;
    int d = (int)(idx >> 13); int kk = (int)(idx & 8191);
    int kp = kk >> 10, din = kk & 1023;
    out[idx] = __float2bfloat16(w[((size_t)d << 13) + din * 8 + kp]);  // patch_w[d][din][kp]
}

// per-layer: in_w [4160][1024] f32 -> [4224][1024] bf16 (zero pad rows) ; out_w [1024][2048] f32 -> bf16
#define CVT_IN_T4 1081344   // NPAD_*1024/4
#define CVT_OUT_T4 524288   // DM_*DI_/4
__global__ __launch_bounds__(256) void k_cvt_layer(const float* __restrict__ in_w, const float* __restrict__ out_w,
                                                   __hip_bfloat16* __restrict__ wBB, __hip_bfloat16* __restrict__ wOB) {
    int i = blockIdx.x * 256 + threadIdx.x;
    if (i < CVT_IN_T4) {
        int idx = i * 4; int row = idx >> 10;
        if (row < DIN_) {
            float4 v = *(const float4*)(in_w + idx);
            wBB[idx + 0] = __float2bfloat16(v.x);
            wBB[idx + 1] = __float2bfloat16(v.y);
            wBB[idx + 2] = __float2bfloat16(v.z);
            wBB[idx + 3] = __float2bfloat16(v.w);
        } else {
            wBB[idx + 0] = __float2bfloat16(0.f);
            wBB[idx + 1] = __float2bfloat16(0.f);
            wBB[idx + 2] = __float2bfloat16(0.f);
            wBB[idx + 3] = __float2bfloat16(0.f);
        }
    } else if (i < CVT_IN_T4 + CVT_OUT_T4) {
        int idx = (i - CVT_IN_T4) * 4;
        float4 v = *(const float4*)(out_w + idx);
        wOB[idx + 0] = __float2bfloat16(v.x);
        wOB[idx + 1] = __float2bfloat16(v.y);
        wOB[idx + 2] = __float2bfloat16(v.z);
        wOB[idx + 3] = __float2bfloat16(v.w);
    }
}

// ---------------- bf16 MFMA GEMM:  C[M,Nstore] = A[M,K] @ BT[Npad,K]^T (+bias)(+resid)(act) ----------------
template<int BM, int BN>
__global__ __launch_bounds__(256) void k_gemm_mfma(
    const ushort* __restrict__ A, const ushort* __restrict__ BT,
    const float* __restrict__ bias, const float* __restrict__ resid,
    float* __restrict__ Cf, __hip_bfloat16* __restrict__ Cb,
    int M, int K, int ldc, int Nstore, int act)
{
    constexpr int BK = 32;
    constexpr int WM = BM / 2, WN = BN / 2;
    constexpr int MR = WM / 16, NR = WN / 16;
    constexpr int ACH = BM * BK / 8;   // 16B chunks in A tile
    constexpr int BCH = BN * BK / 8;
    __shared__ ushort sA[BM * BK];
    __shared__ ushort sB[BN * BK];
    int tid = threadIdx.x;
    int lane = tid & 63, w = tid >> 6;
    int wr = w >> 1, wc = w & 1;
    int m0 = blockIdx.y * BM, n0 = blockIdx.x * BN;

    f32x4 acc[MR][NR] = {};
    for (int k0 = 0; k0 < K; k0 += BK) {
        __syncthreads();
        #pragma unroll
        for (int c = tid; c < ACH; c += 256) {
            int row = c >> 2, col = (c & 3) * 8;
            gload_lds16(A + (size_t)(m0 + row) * K + k0 + col, (char*)sA + c * 16);
        }
        #pragma unroll
        for (int c = tid; c < BCH; c += 256) {
            int row = c >> 2, col = (c & 3) * 8;
            gload_lds16(BT + (size_t)(n0 + row) * K + k0 + col, (char*)sB + c * 16);
        }
        __syncthreads();
        bf16x8 af[MR], bfr[NR];
        #pragma unroll
        for (int m = 0; m < MR; ++m)
            af[m] = *(const bf16x8*)&sA[(wr * WM + m * 16 + (lane & 15)) * BK + (lane >> 4) * 8];
        #pragma unroll
        for (int n = 0; n < NR; ++n)
            bfr[n] = *(const bf16x8*)&sB[(wc * WN + n * 16 + (lane & 15)) * BK + (lane >> 4) * 8];
        #pragma unroll
        for (int m = 0; m < MR; ++m)
            #pragma unroll
            for (int n = 0; n < NR; ++n)
                acc[m][n] = __builtin_amdgcn_mfma_f32_16x16x32_bf16(af[m], bfr[n], acc[m][n], 0, 0, 0);
    }
    #pragma unroll
    for (int m = 0; m < MR; ++m) {
        int row = m0 + wr * WM + m * 16 + (lane >> 4) * 4;
        #pragma unroll
        for (int n = 0; n < NR; ++n) {
            int col = n0 + wc * WN + n * 16 + (lane & 15);
            if (col < Nstore) {
                float bv = bias ? bias[col] : 0.f;
                #pragma unroll
                for (int j = 0; j < 4; ++j) {
                    float v = acc[m][n][j] + bv;
                    if (resid) v += resid[(size_t)(row + j) * ldc + col];
                    if (act) v = silu_f(v);
                    if (Cb) Cb[(size_t)(row + j) * ldc + col] = __float2bfloat16(v);
                    else    Cf[(size_t)(row + j) * ldc + col] = v;
                }
            }
        }
    }
}

// ---------------- misc elementwise ----------------
__global__ __launch_bounds__(256) void k_reverse(const float* __restrict__ hf, float* __restrict__ hb) {
    size_t idx = (size_t)blockIdx.x * 256 + threadIdx.x;
    if (idx >= (size_t)R_ * DM_) return;
    int d = (int)(idx & 1023); size_t r = idx >> 10;
    int l = (int)(r & 127); size_t b = r >> 7;
    hb[idx] = hf[((b * L_) + (L_ - 1 - l)) * DM_ + d];
}

__global__ __launch_bounds__(256) void k_rmsnorm(const float* __restrict__ h, const float* __restrict__ w,
                                                 __hip_bfloat16* __restrict__ u) {
    int r = blockIdx.x; int t = threadIdx.x;
    const float* row = h + (size_t)r * DM_;
    float v[4]; float ss = 0.f;
    #pragma unroll
    for (int i = 0; i < 4; ++i) { v[i] = row[t + 256 * i]; ss += v[i] * v[i]; }
    #pragma unroll
    for (int o = 32; o; o >>= 1) ss += __shfl_xor(ss, o);
    __shared__ float sred[4];
    if ((t & 63) == 0) sred[t >> 6] = ss;
    __syncthreads();
    float tot = sred[0] + sred[1] + sred[2] + sred[3];
    float scale = rsqrtf(tot * (1.0f / DM_) + 1e-5f);
    #pragma unroll
    for (int i = 0; i < 4; ++i)
        u[(size_t)r * DM_ + t + 256 * i] = __float2bfloat16(v[i] * scale * w[t + 256 * i]);
}

__global__ __launch_bounds__(256) void k_dwconv(const float* __restrict__ zx, const float* __restrict__ cw,
                                                const float* __restrict__ cb, float* __restrict__ xbc) {
    size_t idx = (size_t)blockIdx.x * 256 + threadIdx.x;
    if (idx >= (size_t)R_ * CONVD_) return;
    int c = (int)(idx % CONVD_); int r = (int)(idx / CONVD_);
    int l = r & 127;
    float acc = cb[c];
    #pragma unroll
    for (int k = 0; k < 4; ++k) {
        int lp = l - 3 + k;
        if (lp >= 0) acc += zx[((size_t)(r - l + lp)) * DIN_ + DI_ + c] * cw[c * 4 + k];
    }
    xbc[idx] = silu_f(acc);
}

// ---------------- SSM scan: one block per (b,h); dt/dA fused at staging ----------------
__global__ __launch_bounds__(256) void k_scan(const float* __restrict__ xbc, const float* __restrict__ zx,
                                              const float* __restrict__ dt_bias, const float* __restrict__ A_log,
                                              const float* __restrict__ Dh, __hip_bfloat16* __restrict__ ys) {
    __shared__ float xs[L_ * PH_];     // 32 KB, holds x then y in-place
    __shared__ float Bsh[L_ * NS_];
    __shared__ float Csh[L_ * NS_];
    __shared__ float dts[L_];
    __shared__ float dAs[L_];
    int b = blockIdx.x >> 5, h = blockIdx.x & 31;
    int t = threadIdx.x;
    for (int i = t; i < L_ * PH_; i += 256) {
        int l = i >> 6, p = i & 63;
        xs[i] = xbc[((size_t)(b * L_ + l)) * CONVD_ + h * PH_ + p];
    }
    for (int i = t; i < L_ * NS_; i += 256) {
        int l = i >> 4, n = i & 15;
        Bsh[i] = xbc[((size_t)(b * L_ + l)) * CONVD_ + DI_ + n];
        Csh[i] = xbc[((size_t)(b * L_ + l)) * CONVD_ + DI_ + NS_ + n];
    }
    if (t < L_) {
        float v = zx[((size_t)(b * L_ + t)) * DIN_ + 4128 + h] + dt_bias[h];
        float sp = v > 20.f ? v : log1pf(expf(v));
        dts[t] = sp;
        dAs[t] = expf(-expf(A_log[h]) * sp);
    }
    __syncthreads();
    int p = t >> 2, n0 = (t & 3) * 4;
    float Dv = Dh[h];
    float s0 = 0.f, s1 = 0.f, s2 = 0.f, s3 = 0.f;
    for (int l = 0; l < L_; ++l) {
        float x = xs[l * 64 + p];
        float dAv = dAs[l];
        float xdt = x * dts[l];
        s0 = s0 * dAv + xdt * Bsh[l * 16 + n0 + 0];
        s1 = s1 * dAv + xdt * Bsh[l * 16 + n0 + 1];
        s2 = s2 * dAv + xdt * Bsh[l * 16 + n0 + 2];
        s3 = s3 * dAv + xdt * Bsh[l * 16 + n0 + 3];
        float cp = s0 * Csh[l * 16 + n0 + 0] + s1 * Csh[l * 16 + n0 + 1]
                 + s2 * Csh[l * 16 + n0 + 2] + s3 * Csh[l * 16 + n0 + 3];
        cp += __shfl_xor(cp, 1);
        cp += __shfl_xor(cp, 2);
        if ((t & 3) == 0) xs[l * 64 + p] = cp + x * Dv;   // same-wave in-place, safe
    }
    __syncthreads();
    for (int i = t; i < L_ * PH_; i += 256) {
        int l = i >> 6, pp = i & 63;
        float z = zx[((size_t)(b * L_ + l)) * DIN_ + h * PH_ + pp];
        ys[((size_t)(b * L_ + l)) * DI_ + h * PH_ + pp] = __float2bfloat16(xs[i] * silu_f(z));
    }
}

// ---------------- tail ----------------
__global__ __launch_bounds__(256) void k_meanctx(const float* __restrict__ hf, const float* __restrict__ hb,
                                                 float* __restrict__ fused) {
    int b = blockIdx.x, t = threadIdx.x;
    for (int d = t; d < DM_; d += 256) {
        float sf = 0.f, sb = 0.f;
        for (int l = 0; l < L_; ++l) {
            sf += hf[((size_t)b * L_ + l) * DM_ + d];
            sb += hb[((size_t)b * L_ + l) * DM_ + d];
        }
        fused[b * 3072 + d] = sf * (1.f / L_);
        fused[b * 3072 + DM_ + d] = sb * (1.f / L_);
    }
}

__global__ __launch_bounds__(256) void k_aux(const float* __restrict__ y_aux, const float* __restrict__ aux_w,
                                             const float* __restrict__ aux_b, float* __restrict__ fused) {
    int j = blockIdx.x * 256 + threadIdx.x;
    if (j >= DM_) return;
    for (int b = 0; b < B_; ++b) {
        float acc = aux_b[j];
        for (int a = 0; a < 32; ++a) acc += y_aux[b * 32 + a] * aux_w[j * 32 + a];
        fused[b * 3072 + 2 * DM_ + j] = silu_f(acc);
    }
}

__global__ __launch_bounds__(256) void k_basis(const float* __restrict__ x, const float* __restrict__ log_bw,
                                               float* __restrict__ basis, int Din) {
    int idx = blockIdx.x * 256 + threadIdx.x;   // b*Din + d
    if (idx >= 8 * Din) return;
    int d = idx % Din;
    float xv = x[idx];
    float bw = expf(log_bw[d]) + 1e-6f;
    float inv = 1.0f / (2.0f * bw * bw);
    #pragma unroll
    for (int g = 0; g < GG_; ++g) {
        float gg = -2.0f + g * (4.0f / 7.0f);
        float df = xv - gg;
        basis[(size_t)idx * GG_ + g] = expf(-df * df * inv);
    }
}

// K-split dot: wave (row, chunk); chunks = NCH_SP spline chunks + NCH_BASE base chunks.
// partial[(row*NCH + ch)*8 + b]
template<int NCH_SP, int NCH_BASE>
__global__ __launch_bounds__(256) void k_dot_part(const float* __restrict__ xin, const float* __restrict__ basis,
                                                  const float* __restrict__ base_w, const float* __restrict__ spline_w,
                                                  float* __restrict__ partial, int Din, int Dout) {
    constexpr int NCH = NCH_SP + NCH_BASE;
    int gw = (blockIdx.x * 256 + threadIdx.x) >> 6;
    int lane = threadIdx.x & 63;
    if (gw >= Dout * NCH) return;
    int row = gw / NCH, ch = gw % NCH;
    float acc[8] = {};
    if (NCH_SP > 0 && ch < NCH_SP) {
        int Ks = Din * GG_;
        int cl = Ks / NCH_SP;
        const float* sr = spline_w + (size_t)row * Ks + ch * cl;
        const float* br = basis + ch * cl;
        for (int k = lane * 4; k < cl; k += 256) {
            float4 wv = *(const float4*)(sr + k);
            #pragma unroll
            for (int b = 0; b < 8; ++b) {
                float4 bv = *(const float4*)(br + (size_t)b * Ks + k);
                acc[b] += wv.x * bv.x + wv.y * bv.y + wv.z * bv.z + wv.w * bv.w;
            }
        }
    } else {
        int cb = ch - NCH_SP;
        int cl = Din / NCH_BASE;
        const float* wr = base_w + (size_t)row * Din + cb * cl;
        const float* xr = xin + cb * cl;
        for (int k = lane * 4; k < cl; k += 256) {
            float4 wv = *(const float4*)(wr + k);
            #pragma unroll
            for (int b = 0; b < 8; ++b) {
                float4 xv = *(const float4*)(xr + (size_t)b * Din + k);
                acc[b] += wv.x * xv.x + wv.y * xv.y + wv.z * xv.z + wv.w * xv.w;
            }
        }
    }
    #pragma unroll
    for (int b = 0; b < 8; ++b) {
        float v = acc[b];
        #pragma unroll
        for (int o = 32; o; o >>= 1) v += __shfl_xor(v, o);
        acc[b] = v;
    }
    if (lane == 0) {
        #pragma unroll
        for (int b = 0; b < 8; ++b) partial[((size_t)row * NCH + ch) * 8 + b] = acc[b];
    }
}

template<int NCH>
__global__ __launch_bounds__(256) void k_dot_fin(const float* __restrict__ partial, const float* __restrict__ base_b,
                                                 float* __restrict__ out, int Dout) {
    int row = blockIdx.x * 256 + threadIdx.x;
    if (row >= Dout) return;
    float bb = base_b[row];
    #pragma unroll
    for (int b = 0; b < 8; ++b) {
        float s = bb;
        #pragma unroll
        for (int c = 0; c < NCH; ++c) s += partial[((size_t)row * NCH + c) * 8 + b];
        out[(size_t)b * Dout + row] = silu_f(s);
    }
}

__global__ __launch_bounds__(256) void k_heads(const float* __restrict__ fused, const float* __restrict__ hw,
                                               const float* __restrict__ hbias, float* __restrict__ out) {
    int wid = (blockIdx.x * 256 + threadIdx.x) >> 6;   // c*512 + l
    int lane = threadIdx.x & 63;
    if (wid >= COUT_ * OUTL_) return;
    int c = wid >> 9, l = wid & 511;
    const float* wr = hw + (size_t)wid * DM_;
    float acc[8] = {};
    for (int k = lane * 4; k < DM_; k += 256) {
        float4 wv = *(const float4*)(wr + k);
        #pragma unroll
        for (int b = 0; b < 8; ++b) {
            float4 fv = *(const float4*)(fused + (size_t)b * DM_ + k);
            acc[b] += wv.x * fv.x + wv.y * fv.y + wv.z * fv.z + wv.w * fv.w;
        }
    }
    #pragma unroll
    for (int b = 0; b < 8; ++b) {
        float v = acc[b];
        #pragma unroll
        for (int o = 32; o; o >>= 1) v += __shfl_xor(v, o);
        acc[b] = v;
    }
    if (lane == 0) {
        float bb = hbias[wid];
        for (int b = 0; b < 8; ++b) out[((size_t)b * OUTL_ + l) * COUT_ + c] = acc[b] + bb;
    }
}

// ---------------- launch ----------------
extern "C" void kernel_launch(void* const* d_in, const int* in_sizes, int n_in,
                              void* d_out, int out_size, void* d_ws, size_t ws_size,
                              hipStream_t stream) {
    const float* x_prefix = (const float*)d_in[0];
    const float* y_aux    = (const float*)d_in[1];
    const float* pre_w    = (const float*)d_in[2];
    const float* pre_b    = (const float*)d_in[3];
    const float* patch_w  = (const float*)d_in[4];
    const float* patch_b  = (const float*)d_in[5];
    const float* norm_w[2] = {(const float*)d_in[6],  (const float*)d_in[14]};
    const float* in_w[2]   = {(const float*)d_in[7],  (const float*)d_in[15]};
    const float* conv_w[2] = {(const float*)d_in[8],  (const float*)d_in[16]};
    const float* conv_b[2] = {(const float*)d_in[9],  (const float*)d_in[17]};
    const float* A_log[2]  = {(const float*)d_in[10], (const float*)d_in[18]};
    const float* Dvec[2]   = {(const float*)d_in[11], (const float*)d_in[19]};
    const float* dt_b[2]   = {(const float*)d_in[12], (const float*)d_in[20]};
    const float* out_w[2]  = {(const float*)d_in[13], (const float*)d_in[21]};
    const float* aux_w = (const float*)d_in[22];
    const float* aux_b = (const float*)d_in[23];
    const float* k1_lbw = (const float*)d_in[24];
    const float* k1_bw  = (const float*)d_in[25];
    const float* k1_bb  = (const float*)d_in[26];
    const float* k1_sw  = (const float*)d_in[27];
    const float* k2_lbw = (const float*)d_in[28];
    const float* k2_bw  = (const float*)d_in[29];
    const float* k2_bb  = (const float*)d_in[30];
    const float* k2_sw  = (const float*)d_in[31];
    const float* sh_w = (const float*)d_in[32];
    const float* sh_b = (const float*)d_in[33];
    const float* hw   = (const float*)d_in[34];
    const float* hbias= (const float*)d_in[35];
    float* ws = (float*)d_ws;
    float* out = (float*)d_out;

    // workspace layout (float units). Stage region [0..9,863,168) is overlaid by the mamba region.
    const size_t o_ApreB   = 0;           // bf16 8192x320
    const size_t o_wpreTB  = 1310720;     // bf16 1024x320
    const size_t o_x1B     = 1474560;     // bf16 8192x1024
    const size_t o_wpatchTB= 5668864;     // bf16 1024x8192 (ends 9,863,168)
    // mamba overlay:
    const size_t o_uB   = 0;              // bf16 1024x1024
    const size_t o_zx   = 524288;         // f32 1024x4160
    const size_t o_xbc  = 4784128;        // f32 1024x2080
    const size_t o_ysB  = 6914048;        // bf16 1024x2048
    const size_t o_wBB  = 7962624;        // bf16 4224x1024
    const size_t o_wOB  = 10125312;       // bf16 1024x2048 (ends 11,173,888)
    const size_t o_hf   = 11173888;       // f32 1024x1024
    const size_t o_hb   = 12222464;       // f32 1024x1024
    const size_t o_f1   = 13271040;       // 8x3072
    const size_t o_bas1 = 13295616;       // 8x24576
    const size_t o_k1   = 13492224;       // 8x2048
    const size_t o_bas2 = 13508608;       // 8x16384
    const size_t o_k2   = 13639680;       // 8x1024
    const size_t o_f4   = 13647872;       // 8x1024
    const size_t o_part = 13656064;       // 2048*10*8 max
    const size_t total_f = 13819904;
    if (ws_size < total_f * sizeof(float)) return;

    __hip_bfloat16* ApreB   = (__hip_bfloat16*)(ws + o_ApreB);
    __hip_bfloat16* wpreTB  = (__hip_bfloat16*)(ws + o_wpreTB);
    __hip_bfloat16* x1B     = (__hip_bfloat16*)(ws + o_x1B);
    __hip_bfloat16* wpatchTB= (__hip_bfloat16*)(ws + o_wpatchTB);
    __hip_bfloat16* uB      = (__hip_bfloat16*)(ws + o_uB);
    __hip_bfloat16* ysB     = (__hip_bfloat16*)(ws + o_ysB);
    __hip_bfloat16* wBB     = (__hip_bfloat16*)(ws + o_wBB);
    __hip_bfloat16* wOB     = (__hip_bfloat16*)(ws + o_wOB);

    // Stage A: pre-conv as im2col GEMM (silu fused), bf16 out
    k_wpre_T<<<1280, 256, 0, stream>>>(pre_w, wpreTB);
    k_wpatch_T<<<32768, 256, 0, stream>>>(patch_w, wpatchTB);
    k_pre_im2col<<<10240, 256, 0, stream>>>(x_prefix, ApreB);
    k_gemm_mfma<128,128><<<dim3(8, 64), 256, 0, stream>>>(
        (const ushort*)ApreB, (const ushort*)wpreTB, pre_b, nullptr, nullptr, x1B,
        8192, 320, 1024, 1024, 1);
    // Stage B: patch conv as GEMM -> h_f (fp32), then reverse -> h_b
    k_gemm_mfma<64,64><<<dim3(16, 16), 256, 0, stream>>>(
        (const ushort*)x1B, (const ushort*)wpatchTB, patch_b, nullptr, ws + o_hf, nullptr,
        1024, 8192, 1024, 1024, 0);
    k_reverse<<<4096, 256, 0, stream>>>(ws + o_hf, ws + o_hb);

    // Mamba stacks
    for (int dir = 0; dir < 2; ++dir) {
        float* h = ws + (dir == 0 ? o_hf : o_hb);
        for (int i = 0; i < NL_; ++i) {
            k_rmsnorm<<<1024, 256, 0, stream>>>(h, norm_w[dir] + (size_t)i * DM_, uB);
            k_cvt_layer<<<6272, 256, 0, stream>>>(in_w[dir] + (size_t)i * DIN_ * DM_,
                                                  out_w[dir] + (size_t)i * DM_ * DI_, wBB, wOB);
            k_gemm_mfma<128,128><<<dim3(33, 8), 256, 0, stream>>>(
                (const ushort*)uB, (const ushort*)wBB, nullptr, nullptr, ws + o_zx, nullptr,
                1024, 1024, DIN_, DIN_, 0);
            k_dwconv<<<8320, 256, 0, stream>>>(ws + o_zx, conv_w[dir] + (size_t)i * CONVD_ * 4,
                                               conv_b[dir] + (size_t)i * CONVD_, ws + o_xbc);
            k_scan<<<256, 256, 0, stream>>>(ws + o_xbc, ws + o_zx, dt_b[dir] + i * NH_,
                                            A_log[dir] + i * NH_, Dvec[dir] + i * NH_, ysB);
            k_gemm_mfma<64,64><<<dim3(16, 16), 256, 0, stream>>>(
                (const ushort*)ysB, (const ushort*)wOB, nullptr, h, h, nullptr,
                1024, 2048, 1024, 1024, 0);
        }
    }

    // Tail
    k_meanctx<<<8, 256, 0, stream>>>(ws + o_hf, ws + o_hb, ws + o_f1);
    k_aux<<<4, 256, 0, stream>>>(y_aux, aux_w, aux_b, ws + o_f1);
    k_basis<<<96, 256, 0, stream>>>(ws + o_f1, k1_lbw, ws + o_bas1, 3072);
    k_dot_part<8,2><<<5120, 256, 0, stream>>>(ws + o_f1, ws + o_bas1, k1_bw, k1_sw, ws + o_part, 3072, 2048);
    k_dot_fin<10><<<8, 256, 0, stream>>>(ws + o_part, k1_bb, ws + o_k1, 2048);
    k_basis<<<64, 256, 0, stream>>>(ws + o_k1, k2_lbw, ws + o_bas2, 2048);
    k_dot_part<8,2><<<2560, 256, 0, stream>>>(ws + o_k1, ws + o_bas2, k2_bw, k2_sw, ws + o_part, 2048, 1024);
    k_dot_fin<10><<<4, 256, 0, stream>>>(ws + o_part, k2_bb, ws + o_k2, 1024);
    k_dot_part<0,4><<<1024, 256, 0, stream>>>(ws + o_k2, nullptr, sh_w, nullptr, ws + o_part, 1024, 1024);
    k_dot_fin<4><<<4, 256, 0, stream>>>(ws + o_part, sh_b, ws + o_f4, 1024);
    k_heads<<<8192, 256, 0, stream>>>(ws + o_f4, hw, hbias, out);
}